// Round 3
// baseline (167.484 us; speedup 1.0000x reference)
//
#include <hip/hip_runtime.h>
#include <cstdint>

#define HW 4096

typedef __attribute__((ext_vector_type(8))) short bf16x8;
typedef __attribute__((ext_vector_type(4))) float f32x4;

__device__ __forceinline__ short f2bf(float f) {
    union { float f; uint32_t u; } v; v.f = f;
    uint32_t u = v.u;
    uint32_t r = (u + 0x7FFFu + ((u >> 16) & 1u)) >> 16;
    return (short)(r & 0xFFFFu);
}
__device__ __forceinline__ uint32_t cvtpk(float lo, float hi) {
    uint32_t r;
    asm("v_cvt_pk_bf16_f32 %0, %1, %2" : "=v"(r) : "v"(lo), "v"(hi));
    return r;
}
__device__ __forceinline__ float blo(uint32_t u) { return __uint_as_float(u << 16); }
__device__ __forceinline__ float bhi(uint32_t u) { return __uint_as_float(u & 0xFFFF0000u); }
__device__ __forceinline__ void glds16(const void* g, void* l) {
    __builtin_amdgcn_global_load_lds(
        (const __attribute__((address_space(1))) void*)g,
        (__attribute__((address_space(3))) void*)l, 16, 0, 0);
}

// ---------------------------------------------------------------------------
// Kernel 1: transpose x[b][c][hw] (fp32) -> xT[b][hw][c] (bf16).
// ---------------------------------------------------------------------------
__global__ __launch_bounds__(256) void k_xt(
    const float* __restrict__ x, unsigned short* __restrict__ xT)
{
    __shared__ unsigned short s[64][65];
    const int t = threadIdx.x, lane = t & 63, grp = t >> 6;
    const int hw0 = blockIdx.x * 64, c0 = blockIdx.y * 64, b = blockIdx.z;
#pragma unroll
    for (int j = 0; j < 16; ++j) {
        int cc = grp * 16 + j;
        float v = x[((size_t)(b * 256 + c0 + cc)) * HW + hw0 + lane];
        s[cc][lane] = (unsigned short)f2bf(v);
    }
    __syncthreads();
#pragma unroll
    for (int j = 0; j < 16; ++j) {
        int hw2 = grp * 16 + j;
        xT[((size_t)b * HW + hw0 + hw2) * 256 + c0 + lane] = s[lane][hw2];
    }
}

// ---------------------------------------------------------------------------
// Kernel 2 (merged): both weight conversions in one launch.
// e < 589824: deformable-GEMM A  a2[o][dg*1152 + tap*128 + c]
// else      : offset-conv wTb, padded to 64 rows, r = tap*256 + c.
// ---------------------------------------------------------------------------
__global__ __launch_bounds__(256) void k_wcvt_all(
    const float* __restrict__ weight, const float* __restrict__ w_off,
    short* __restrict__ a2, short* __restrict__ wTb)
{
    int e = blockIdx.x * 256 + threadIdx.x;     // 737280 total
    if (e < 589824) {
        int o = e / 2304, r = e - o * 2304;
        int dg = r / 1152, r2 = r - dg * 1152;
        int tap = r2 >> 7, c = r2 & 127;
        a2[e] = f2bf(weight[o * 2304 + (dg * 128 + c) * 9 + tap]);
    } else {
        int e2 = e - 589824;
        int o = e2 / 2304, r = e2 - o * 2304;
        int tap = r >> 8, c = r & 255;
        wTb[e2] = (o < 54) ? f2bf(w_off[(o * 256 + c) * 9 + tap]) : (short)0;
    }
}

// ---------------------------------------------------------------------------
// Kernel 3: offset conv as MFMA GEMM, split-K x4, software-pipelined.
// ---------------------------------------------------------------------------
__global__ __launch_bounds__(256, 4) void k_omgemm(
    const short* __restrict__ wTb, const unsigned short* __restrict__ xT,
    float* __restrict__ om2p)
{
    __shared__ short As[2][64 * 32];
    __shared__ short Bs[2][64 * 32];
    const int t = threadIdx.x;
    const int wid = __builtin_amdgcn_readfirstlane(t >> 6);
    const int lane = t & 63, quad = lane >> 4, l16 = lane & 15;
    const int n0 = blockIdx.x * 64, b = n0 >> 12;
    const int ks = blockIdx.y;          // 0..3 -> chunks ks*18 .. ks*18+17
    const int nr = t >> 2;
    const int ksh = (t & 3) * 8;
    const int px = (n0 + nr) & 4095, h = px >> 6, w = px & 63;
    const unsigned short* xb = xT + (size_t)b * HW * 256;
    const int cbase = ks * 18;

    auto loadB = [&](int c) -> uint4 {
        int tap = c >> 3, c0 = (c & 7) * 32;
        int hh = h + tap / 3 - 1, ww = w + tap % 3 - 1;
        uint4 bv = {0u, 0u, 0u, 0u};
        if (hh >= 0 && hh < 64 && ww >= 0 && ww < 64)
            bv = *(const uint4*)(xb + (size_t)(hh * 64 + ww) * 256 + c0 + ksh);
        return bv;
    };

    f32x4 acc[4];
#pragma unroll
    for (int i = 0; i < 4; ++i) acc[i] = (f32x4){0.f, 0.f, 0.f, 0.f};

    uint4 bv[2];
    bv[0] = loadB(cbase);
    glds16(wTb + (size_t)nr * 2304 + cbase * 32 + ksh, &As[0][t * 8]);
    *(uint4*)&Bs[0][t * 8] = bv[0];
    bv[1] = loadB(cbase + 1);

#pragma unroll 2
    for (int i = 0; i < 18; ++i) {
        const int p = i & 1;
        __syncthreads();
        if (i < 17) {
            glds16(wTb + (size_t)nr * 2304 + (cbase + i + 1) * 32 + ksh,
                   &As[1 - p][t * 8]);
            *(uint4*)&Bs[1 - p][t * 8] = bv[(i + 1) & 1];
        }
        if (i + 2 < 18) bv[i & 1] = loadB(cbase + i + 2);
        bf16x8 bf = *(const bf16x8*)&Bs[p][(wid * 16 + l16) * 32 + quad * 8];
#pragma unroll
        for (int mi = 0; mi < 4; ++mi) {
            bf16x8 af = *(const bf16x8*)&As[p][(mi * 16 + l16) * 32 + quad * 8];
            acc[mi] = __builtin_amdgcn_mfma_f32_16x16x32_bf16(af, bf, acc[mi], 0, 0, 0);
        }
    }
    const int n = n0 + wid * 16 + l16;
#pragma unroll
    for (int mi = 0; mi < 4; ++mi)
#pragma unroll
        for (int i = 0; i < 4; ++i)
            om2p[(size_t)(ks * 64 + mi * 16 + quad * 4 + i) * 16384 + n] = acc[mi][i];
}

// ---------------------------------------------------------------------------
// Kernel 5: sampling plan (sums 4 split-K partials). Per e = s*16384+n:
// 4 bilinear weights (validity & sigmoid folded) + 4 byte offsets (<<9).
// ---------------------------------------------------------------------------
__global__ __launch_bounds__(256) void k_plan(
    const float* __restrict__ om2p, const float* __restrict__ b_off,
    float4* __restrict__ planw, int4* __restrict__ plani)
{
    int e = blockIdx.x * 256 + threadIdx.x;      // 294912
    int n = e & 16383, s = e >> 14;
    int dg = s >= 9 ? 1 : 0, tap = s - dg * 9;
    int h = (n >> 6) & 63, w = n & 63;
    int cdy = dg * 18 + tap, cdx = cdy + 9, cms = 36 + dg * 9 + tap;
    float dy = b_off[cdy], dx = b_off[cdx], ms = b_off[cms];
#pragma unroll
    for (int cs = 0; cs < 4; ++cs) {
        const float* p = om2p + (size_t)cs * 64 * 16384;
        dy += p[(size_t)cdy * 16384 + n];
        dx += p[(size_t)cdx * 16384 + n];
        ms += p[(size_t)cms * 16384 + n];
    }
    ms = 1.f / (1.f + __expf(-ms));
    float py = dy + (float)(h + tap / 3 - 1);
    float qx = dx + (float)(w + tap % 3 - 1);
    float y0f = floorf(py), x0f = floorf(qx);
    float wy1 = py - y0f, wx1 = qx - x0f;
    float wy0 = 1.f - wy1, wx0 = 1.f - wx1;
    int y0 = (int)y0f, x0 = (int)x0f;
    int y1 = y0 + 1, x1 = x0 + 1;
    bool vy0 = (y0 >= 0) & (y0 < 64), vy1 = (y1 >= 0) & (y1 < 64);
    bool vx0 = (x0 >= 0) & (x0 < 64), vx1 = (x1 >= 0) & (x1 < 64);
    int cy0 = min(max(y0, 0), 63), cy1 = min(max(y1, 0), 63);
    int cx0 = min(max(x0, 0), 63), cx1 = min(max(x1, 0), 63);
    float4 wv;
    wv.x = (vy0 && vx0) ? wy0 * wx0 * ms : 0.f;
    wv.y = (vy0 && vx1) ? wy0 * wx1 * ms : 0.f;
    wv.z = (vy1 && vx0) ? wy1 * wx0 * ms : 0.f;
    wv.w = (vy1 && vx1) ? wy1 * wx1 * ms : 0.f;
    int4 iv = make_int4((cy0 * 64 + cx0) << 9, (cy0 * 64 + cx1) << 9,
                        (cy1 * 64 + cx0) << 9, (cy1 * 64 + cx1) << 9);
    planw[e] = wv;
    plani[e] = iv;
}

// ---------------------------------------------------------------------------
// Kernel 6: FUSED sampling + GEMM, m-merged, 2 BLOCKS/CU.
// 512 threads (8 waves); tile 64 px x 256 m; K-step 64 (36 iters; s = i>>1,
// half = i&1). Each wave owns a 32m x 64n slice (acc[2][4]). Gather + pack
// still done ONCE per pixel. LDS exactly 80 KB (As 2x2x16KB glds16-staged,
// Bs 2x2x4KB) -> 2 blocks/CU x 8 waves = 16 waves/CU. The two resident
// blocks alternate phases at barriers, covering each other's vmcnt(0)
// drains (round-2's single-block layout had zero cover -> ~70% stall).
// XOR granule swizzle g^((row>>1)&3) on glds16 SOURCE / Bs write, matched
// on fragment reads. Plan slots rotate by s-parity; packwrite precedes the
// planload that reuses its slot. unroll 4 keeps slot indices static.
// ---------------------------------------------------------------------------
__global__ __launch_bounds__(512, 4) void k_fused(
    const short* __restrict__ A, const unsigned short* __restrict__ xT,
    const float4* __restrict__ planw, const int4* __restrict__ plani,
    const float* __restrict__ bias, float* __restrict__ out)
{
    __shared__ short As[2][2][256 * 32];   // [buf][ss][row*32 + g*8] 64 KB
    __shared__ short Bs[2][2][64 * 32];    // [buf][ss][px*32 + g*8]  16 KB
    const int t = threadIdx.x;
    const int wid = __builtin_amdgcn_readfirstlane(t >> 6);  // 0..7
    const int lane = t & 63;
    const int quad = lane >> 4, l16 = lane & 15;

    // XCD swizzle: 256 blocks, 8 XCDs, 32 contiguous bn per XCD.
    const int lin = blockIdx.x;
    const int bn = ((lin & 7) << 5) | (lin >> 3);

    const int n0 = bn * 64, b = n0 >> 12;
    const char* xbb = (const char*)xT + (size_t)b * HW * 512;
    const int px = t >> 3;          // 0..63: pixel this thread samples
    const int cc2 = (t >> 2) & 1;   // 32-ch chunk within the K=64 step
    const int q8 = (t & 3) * 8;     // 8-ch granule within chunk
    const int n = n0 + px;

    f32x4 acc[2][4];
#pragma unroll
    for (int i = 0; i < 2; ++i)
#pragma unroll
        for (int j = 0; j < 4; ++j) acc[i][j] = (f32x4){0.f, 0.f, 0.f, 0.f};

    float4 pw[2];
    int4 pi[2];
    uint4 g[2][4];

    auto planload = [&](int S) {
        pw[S & 1] = planw[(size_t)S * 16384 + n];
        pi[S & 1] = plani[(size_t)S * 16384 + n];
    };
    // gather K-step j (= 2*s + half): this thread fetches its 8-ch granule,
    // 4 bilinear corners.
    auto gather = [&](int j, uint4* gd) {
        const int s = j >> 1;
        const int cb = ((s >= 9 ? 128 : 0) + (j & 1) * 64 + cc2 * 32 + q8) * 2;
        const int4 i4 = pi[s & 1];
        gd[0] = *(const uint4*)(xbb + i4.x + cb);
        gd[1] = *(const uint4*)(xbb + i4.y + cb);
        gd[2] = *(const uint4*)(xbb + i4.z + cb);
        gd[3] = *(const uint4*)(xbb + i4.w + cb);
    };
    const int ar = t >> 2, aq = t & 3;
    auto stageA = [&](int j, int buf) {
        const int s = j >> 1;
        const int kb = s * 128 + (j & 1) * 64;
#pragma unroll
        for (int r = 0; r < 2; ++r) {
            const int row = ar + r * 128;
            const int asw = (aq ^ ((row >> 1) & 3)) * 8;   // swizzled SOURCE
#pragma unroll
            for (int ss = 0; ss < 2; ++ss)
                glds16(A + (size_t)row * 2304 + kb + ss * 32 + asw,
                       &As[buf][ss][row * 32 + aq * 8]);
        }
    };
    const int bsw = ((t & 3) ^ ((px >> 1) & 3)) * 8;       // swizzled WRITE
    auto packwrite = [&](int j, int buf) {
        const float4 w4 = pw[(j >> 1) & 1];
        const uint4* gd = g[j & 1];
        float a0 = w4.x * blo(gd[0].x) + w4.y * blo(gd[1].x) + w4.z * blo(gd[2].x) + w4.w * blo(gd[3].x);
        float a1 = w4.x * bhi(gd[0].x) + w4.y * bhi(gd[1].x) + w4.z * bhi(gd[2].x) + w4.w * bhi(gd[3].x);
        float a2v = w4.x * blo(gd[0].y) + w4.y * blo(gd[1].y) + w4.z * blo(gd[2].y) + w4.w * blo(gd[3].y);
        float a3 = w4.x * bhi(gd[0].y) + w4.y * bhi(gd[1].y) + w4.z * bhi(gd[2].y) + w4.w * bhi(gd[3].y);
        float a4 = w4.x * blo(gd[0].z) + w4.y * blo(gd[1].z) + w4.z * blo(gd[2].z) + w4.w * blo(gd[3].z);
        float a5 = w4.x * bhi(gd[0].z) + w4.y * bhi(gd[1].z) + w4.z * bhi(gd[2].z) + w4.w * bhi(gd[3].z);
        float a6 = w4.x * blo(gd[0].w) + w4.y * blo(gd[1].w) + w4.z * blo(gd[2].w) + w4.w * blo(gd[3].w);
        float a7 = w4.x * bhi(gd[0].w) + w4.y * bhi(gd[1].w) + w4.z * bhi(gd[2].w) + w4.w * bhi(gd[3].w);
        uint4 o;
        o.x = cvtpk(a0, a1); o.y = cvtpk(a2v, a3);
        o.z = cvtpk(a4, a5); o.w = cvtpk(a6, a7);
        *(uint4*)&Bs[buf][cc2][px * 32 + bsw] = o;
    };

    // prologue: K-step 0 into buf 0; step 1 gathered; plan slots hold s=0,1
    planload(0);
    gather(0, g[0]);
    stageA(0, 0);
    packwrite(0, 0);
    planload(1);
    gather(1, g[1]);

#pragma unroll 4
    for (int i = 0; i < 36; ++i) {
        const int p = i & 1;
        __syncthreads();
        if (i < 35) {
            stageA(i + 1, 1 - p);
            packwrite(i + 1, 1 - p);    // uses slot ((i+1)>>1)&1 ...
        }
        if (((i & 1) == 0) && (i + 4 < 36))
            planload((i + 4) >> 1);     // ... which this may overwrite: AFTER
        if (i + 2 < 36) gather(i + 2, g[i & 1]);
#pragma unroll
        for (int ss = 0; ss < 2; ++ss) {
            bf16x8 bfr[4];
#pragma unroll
            for (int ni = 0; ni < 4; ++ni) {
                const int row = ni * 16 + l16;
                bfr[ni] = *(const bf16x8*)&Bs[p][ss][row * 32 + (quad ^ ((row >> 1) & 3)) * 8];
            }
#pragma unroll
            for (int mi = 0; mi < 2; ++mi) {
                const int row = wid * 32 + mi * 16 + l16;
                bf16x8 af = *(const bf16x8*)&As[p][ss][row * 32 + (quad ^ ((row >> 1) & 3)) * 8];
#pragma unroll
                for (int ni = 0; ni < 4; ++ni)
                    acc[mi][ni] = __builtin_amdgcn_mfma_f32_16x16x32_bf16(
                        af, bfr[ni], acc[mi][ni], 0, 0, 0);
            }
        }
    }

    const int m0 = wid * 32;
#pragma unroll
    for (int mi = 0; mi < 2; ++mi)
#pragma unroll
        for (int ni = 0; ni < 4; ++ni) {
            int nn = n0 + ni * 16 + l16;
            int bidx = nn >> 12, hw = nn & 4095;
            float* op = out + (size_t)bidx * 256 * 4096 + hw;
#pragma unroll
            for (int r = 0; r < 4; ++r) {
                int m = m0 + mi * 16 + quad * 4 + r;
                op[(size_t)m * 4096] = acc[mi][ni][r] + bias[m];
            }
        }
}

// ---------------------------------------------------------------------------
extern "C" void kernel_launch(void* const* d_in, const int* in_sizes, int n_in,
                              void* d_out, int out_size, void* d_ws, size_t ws_size,
                              hipStream_t stream)
{
    const float* x      = (const float*)d_in[0];
    const float* w_off  = (const float*)d_in[1];
    const float* b_off  = (const float*)d_in[2];
    const float* weight = (const float*)d_in[3];
    const float* bias   = (const float*)d_in[4];
    float* out = (float*)d_out;
    char* ws = (char*)d_ws;

    // ws layout (19,300,352 B total):
    unsigned short* xT   = (unsigned short*)(ws);           //  8,388,608
    short*          a2   = (short*)(ws + 8388608);          //  1,179,648
    short*          wTb  = (short*)(ws + 9568256);          //    294,912
    float4*         planw= (float4*)(ws + 9863168);         //  4,718,592
    int4*           plani= (int4*)(ws + 14581760);          //  4,718,592 -> 19,300,352
    // om2p (4 split-K partials) aliases d_out; fully consumed by k_plan
    // before k_fused overwrites d_out. Stream-ordered.
    float*          om2p = (float*)d_out;

    hipLaunchKernelGGL(k_xt, dim3(64, 4, 4), dim3(256), 0, stream, x, xT);
    hipLaunchKernelGGL(k_wcvt_all, dim3(2880), dim3(256), 0, stream,
                       weight, w_off, a2, wTb);
    hipLaunchKernelGGL(k_omgemm, dim3(256, 4), dim3(256), 0, stream, wTb, xT, om2p);
    hipLaunchKernelGGL(k_plan, dim3(1152), dim3(256), 0, stream, om2p, b_off, planw, plani);
    hipLaunchKernelGGL(k_fused, dim3(256), dim3(512), 0, stream,
                       a2, xT, planw, plani, bias, out);
}

// Round 4
// 142.251 us; speedup vs baseline: 1.1774x; 1.1774x over previous
//
#include <hip/hip_runtime.h>
#include <cstdint>

#define HW 4096

typedef __attribute__((ext_vector_type(8))) short bf16x8;
typedef __attribute__((ext_vector_type(4))) float f32x4;

__device__ __forceinline__ short f2bf(float f) {
    union { float f; uint32_t u; } v; v.f = f;
    uint32_t u = v.u;
    uint32_t r = (u + 0x7FFFu + ((u >> 16) & 1u)) >> 16;
    return (short)(r & 0xFFFFu);
}
__device__ __forceinline__ uint32_t cvtpk(float lo, float hi) {
    uint32_t r;
    asm("v_cvt_pk_bf16_f32 %0, %1, %2" : "=v"(r) : "v"(lo), "v"(hi));
    return r;
}
__device__ __forceinline__ float blo(uint32_t u) { return __uint_as_float(u << 16); }
__device__ __forceinline__ float bhi(uint32_t u) { return __uint_as_float(u & 0xFFFF0000u); }
__device__ __forceinline__ void glds16(const void* g, void* l) {
    __builtin_amdgcn_global_load_lds(
        (const __attribute__((address_space(1))) void*)g,
        (__attribute__((address_space(3))) void*)l, 16, 0, 0);
}

// ---------------------------------------------------------------------------
// Kernel 1: transpose x[b][c][hw] (fp32) -> xT[b][hw][c] (bf16).
// ---------------------------------------------------------------------------
__global__ __launch_bounds__(256) void k_xt(
    const float* __restrict__ x, unsigned short* __restrict__ xT)
{
    __shared__ unsigned short s[64][65];
    const int t = threadIdx.x, lane = t & 63, grp = t >> 6;
    const int hw0 = blockIdx.x * 64, c0 = blockIdx.y * 64, b = blockIdx.z;
#pragma unroll
    for (int j = 0; j < 16; ++j) {
        int cc = grp * 16 + j;
        float v = x[((size_t)(b * 256 + c0 + cc)) * HW + hw0 + lane];
        s[cc][lane] = (unsigned short)f2bf(v);
    }
    __syncthreads();
#pragma unroll
    for (int j = 0; j < 16; ++j) {
        int hw2 = grp * 16 + j;
        xT[((size_t)b * HW + hw0 + hw2) * 256 + c0 + lane] = s[lane][hw2];
    }
}

// ---------------------------------------------------------------------------
// Kernel 2 (merged): both weight conversions in one launch.
// ---------------------------------------------------------------------------
__global__ __launch_bounds__(256) void k_wcvt_all(
    const float* __restrict__ weight, const float* __restrict__ w_off,
    short* __restrict__ a2, short* __restrict__ wTb)
{
    int e = blockIdx.x * 256 + threadIdx.x;     // 737280 total
    if (e < 589824) {
        int o = e / 2304, r = e - o * 2304;
        int dg = r / 1152, r2 = r - dg * 1152;
        int tap = r2 >> 7, c = r2 & 127;
        a2[e] = f2bf(weight[o * 2304 + (dg * 128 + c) * 9 + tap]);
    } else {
        int e2 = e - 589824;
        int o = e2 / 2304, r = e2 - o * 2304;
        int tap = r >> 8, c = r & 255;
        wTb[e2] = (o < 54) ? f2bf(w_off[(o * 256 + c) * 9 + tap]) : (short)0;
    }
}

// ---------------------------------------------------------------------------
// Kernel 3: offset conv as MFMA GEMM, split-K x4, software-pipelined.
// ---------------------------------------------------------------------------
__global__ __launch_bounds__(256, 4) void k_omgemm(
    const short* __restrict__ wTb, const unsigned short* __restrict__ xT,
    float* __restrict__ om2p)
{
    __shared__ short As[2][64 * 32];
    __shared__ short Bs[2][64 * 32];
    const int t = threadIdx.x;
    const int wid = __builtin_amdgcn_readfirstlane(t >> 6);
    const int lane = t & 63, quad = lane >> 4, l16 = lane & 15;
    const int n0 = blockIdx.x * 64, b = n0 >> 12;
    const int ks = blockIdx.y;          // 0..3 -> chunks ks*18 .. ks*18+17
    const int nr = t >> 2;
    const int ksh = (t & 3) * 8;
    const int px = (n0 + nr) & 4095, h = px >> 6, w = px & 63;
    const unsigned short* xb = xT + (size_t)b * HW * 256;
    const int cbase = ks * 18;

    auto loadB = [&](int c) -> uint4 {
        int tap = c >> 3, c0 = (c & 7) * 32;
        int hh = h + tap / 3 - 1, ww = w + tap % 3 - 1;
        uint4 bv = {0u, 0u, 0u, 0u};
        if (hh >= 0 && hh < 64 && ww >= 0 && ww < 64)
            bv = *(const uint4*)(xb + (size_t)(hh * 64 + ww) * 256 + c0 + ksh);
        return bv;
    };

    f32x4 acc[4];
#pragma unroll
    for (int i = 0; i < 4; ++i) acc[i] = (f32x4){0.f, 0.f, 0.f, 0.f};

    uint4 bv[2];
    bv[0] = loadB(cbase);
    glds16(wTb + (size_t)nr * 2304 + cbase * 32 + ksh, &As[0][t * 8]);
    *(uint4*)&Bs[0][t * 8] = bv[0];
    bv[1] = loadB(cbase + 1);

#pragma unroll 2
    for (int i = 0; i < 18; ++i) {
        const int p = i & 1;
        __syncthreads();
        if (i < 17) {
            glds16(wTb + (size_t)nr * 2304 + (cbase + i + 1) * 32 + ksh,
                   &As[1 - p][t * 8]);
            *(uint4*)&Bs[1 - p][t * 8] = bv[(i + 1) & 1];
        }
        if (i + 2 < 18) bv[i & 1] = loadB(cbase + i + 2);
        bf16x8 bf = *(const bf16x8*)&Bs[p][(wid * 16 + l16) * 32 + quad * 8];
#pragma unroll
        for (int mi = 0; mi < 4; ++mi) {
            bf16x8 af = *(const bf16x8*)&As[p][(mi * 16 + l16) * 32 + quad * 8];
            acc[mi] = __builtin_amdgcn_mfma_f32_16x16x32_bf16(af, bf, acc[mi], 0, 0, 0);
        }
    }
    const int n = n0 + wid * 16 + l16;
#pragma unroll
    for (int mi = 0; mi < 4; ++mi)
#pragma unroll
        for (int i = 0; i < 4; ++i)
            om2p[(size_t)(ks * 64 + mi * 16 + quad * 4 + i) * 16384 + n] = acc[mi][i];
}

// ---------------------------------------------------------------------------
// Kernel 5: sampling plan (sums 4 split-K partials).
// ---------------------------------------------------------------------------
__global__ __launch_bounds__(256) void k_plan(
    const float* __restrict__ om2p, const float* __restrict__ b_off,
    float4* __restrict__ planw, int4* __restrict__ plani)
{
    int e = blockIdx.x * 256 + threadIdx.x;      // 294912
    int n = e & 16383, s = e >> 14;
    int dg = s >= 9 ? 1 : 0, tap = s - dg * 9;
    int h = (n >> 6) & 63, w = n & 63;
    int cdy = dg * 18 + tap, cdx = cdy + 9, cms = 36 + dg * 9 + tap;
    float dy = b_off[cdy], dx = b_off[cdx], ms = b_off[cms];
#pragma unroll
    for (int cs = 0; cs < 4; ++cs) {
        const float* p = om2p + (size_t)cs * 64 * 16384;
        dy += p[(size_t)cdy * 16384 + n];
        dx += p[(size_t)cdx * 16384 + n];
        ms += p[(size_t)cms * 16384 + n];
    }
    ms = 1.f / (1.f + __expf(-ms));
    float py = dy + (float)(h + tap / 3 - 1);
    float qx = dx + (float)(w + tap % 3 - 1);
    float y0f = floorf(py), x0f = floorf(qx);
    float wy1 = py - y0f, wx1 = qx - x0f;
    float wy0 = 1.f - wy1, wx0 = 1.f - wx1;
    int y0 = (int)y0f, x0 = (int)x0f;
    int y1 = y0 + 1, x1 = x0 + 1;
    bool vy0 = (y0 >= 0) & (y0 < 64), vy1 = (y1 >= 0) & (y1 < 64);
    bool vx0 = (x0 >= 0) & (x0 < 64), vx1 = (x1 >= 0) & (x1 < 64);
    int cy0 = min(max(y0, 0), 63), cy1 = min(max(y1, 0), 63);
    int cx0 = min(max(x0, 0), 63), cx1 = min(max(x1, 0), 63);
    float4 wv;
    wv.x = (vy0 && vx0) ? wy0 * wx0 * ms : 0.f;
    wv.y = (vy0 && vx1) ? wy0 * wx1 * ms : 0.f;
    wv.z = (vy1 && vx0) ? wy1 * wx0 * ms : 0.f;
    wv.w = (vy1 && vx1) ? wy1 * wx1 * ms : 0.f;
    int4 iv = make_int4((cy0 * 64 + cx0) << 9, (cy0 * 64 + cx1) << 9,
                        (cy1 * 64 + cx0) << 9, (cy1 * 64 + cx1) << 9);
    planw[e] = wv;
    plani[e] = iv;
}

// ---------------------------------------------------------------------------
// Kernel 6: FUSED sampling + GEMM, m-merged (round-2 structure: 1024 thr,
// 16 waves, 256m x 64px tile, K=128/tap, 18 iters, LDS 160 KB) + COUNTED
// vmcnt BARRIERS (T3/T4). Per iter, vmem issue order is pinned:
//   [stage x4 glds16][pwload][piload][gather x4]
// and each barrier waits s_waitcnt vmcnt(4) lgkmcnt(0): retires the stage
// glds16 (As[1-p] complete for all waves after s_barrier) but leaves the
// 4 gathers IN FLIGHT across the barrier (consumed by packwrite next iter
// via compiler-counted waits). Final barrier: only stage outstanding ->
// vmcnt(0). pi is loaded one tap earlier than pw so gather's address dep
// has a full iteration of cover. Accounting (outstanding at barrier top):
// iters 1..15: [st4,pw,pi,g4]=10 -> vmcnt(4) OK; iter16: [st4,pw,g4]=9 OK;
// iter17: [st4] -> vmcnt(0).
// ---------------------------------------------------------------------------
__global__ __launch_bounds__(1024, 4) void k_fused(
    const short* __restrict__ A, const unsigned short* __restrict__ xT,
    const float4* __restrict__ planw, const int4* __restrict__ plani,
    const float* __restrict__ bias, float* __restrict__ out)
{
    __shared__ short As[2][4][256 * 32];   // [buf][ss][row*32 + g*8] 128 KB
    __shared__ short Bs[2][4][64 * 32];    // [buf][ss][px*32 + g*8]   32 KB
    const int t = threadIdx.x;
    const int wid = __builtin_amdgcn_readfirstlane(t >> 6);  // 0..15
    const int lane = t & 63;
    const int quad = lane >> 4, l16 = lane & 15;
    const int wr = wid & 7, wc = wid >> 3;   // 8 m-slices x 2 n-halves

    // XCD swizzle: 256 blocks, 8 XCDs, 32 contiguous bn per XCD.
    const int lin = blockIdx.x;
    const int bn = ((lin & 7) << 5) | (lin >> 3);

    const int n0 = bn * 64, b = n0 >> 12;
    const char* xbb = (const char*)xT + (size_t)b * HW * 512;
    const int px = t >> 4;          // 0..63: pixel this thread samples
    const int cc = (t >> 2) & 3;    // 32-ch chunk within the K=128 tap
    const int q8 = (t & 3) * 8;     // 8-ch granule within chunk
    const int n = n0 + px;

    f32x4 acc[2][2];
#pragma unroll
    for (int i = 0; i < 2; ++i)
#pragma unroll
        for (int j = 0; j < 2; ++j) acc[i][j] = (f32x4){0.f, 0.f, 0.f, 0.f};

    float4 pw[2];
    int4 pi[2];
    uint4 g[2][4];

    auto pwload = [&](int S) { pw[S & 1] = planw[(size_t)S * 16384 + n]; };
    auto piload = [&](int S) { pi[S & 1] = plani[(size_t)S * 16384 + n]; };
    // gather tap j: this thread fetches its chunk cc, 8 channels, 4 corners.
    auto gather = [&](int j, uint4* gd) {
        const int cb = ((j >= 9 ? 128 : 0) + cc * 32 + q8) * 2;
        const int4 i4 = pi[j & 1];
        gd[0] = *(const uint4*)(xbb + i4.x + cb);
        gd[1] = *(const uint4*)(xbb + i4.y + cb);
        gd[2] = *(const uint4*)(xbb + i4.z + cb);
        gd[3] = *(const uint4*)(xbb + i4.w + cb);
    };
    const int arow = t >> 2;                       // 0..255
    const int aq = t & 3;
    const int asw = (aq ^ ((arow >> 1) & 3)) * 8;  // swizzled SOURCE granule
    auto stageA = [&](int j, int buf) {
#pragma unroll
        for (int ss = 0; ss < 4; ++ss)
            glds16(A + (size_t)arow * 2304 + (4 * j + ss) * 32 + asw,
                   &As[buf][ss][arow * 32 + aq * 8]);
    };
    const int bsw = ((t & 3) ^ ((px >> 1) & 3)) * 8;  // swizzled WRITE granule
    auto packwrite = [&](int j, int buf) {
        const float4 w4 = pw[j & 1];
        const uint4* gd = g[j & 1];
        float a0 = w4.x * blo(gd[0].x) + w4.y * blo(gd[1].x) + w4.z * blo(gd[2].x) + w4.w * blo(gd[3].x);
        float a1 = w4.x * bhi(gd[0].x) + w4.y * bhi(gd[1].x) + w4.z * bhi(gd[2].x) + w4.w * bhi(gd[3].x);
        float a2v = w4.x * blo(gd[0].y) + w4.y * blo(gd[1].y) + w4.z * blo(gd[2].y) + w4.w * blo(gd[3].y);
        float a3 = w4.x * bhi(gd[0].y) + w4.y * bhi(gd[1].y) + w4.z * bhi(gd[2].y) + w4.w * bhi(gd[3].y);
        float a4 = w4.x * blo(gd[0].z) + w4.y * blo(gd[1].z) + w4.z * blo(gd[2].z) + w4.w * blo(gd[3].z);
        float a5 = w4.x * bhi(gd[0].z) + w4.y * bhi(gd[1].z) + w4.z * bhi(gd[2].z) + w4.w * bhi(gd[3].z);
        float a6 = w4.x * blo(gd[0].w) + w4.y * blo(gd[1].w) + w4.z * blo(gd[2].w) + w4.w * blo(gd[3].w);
        float a7 = w4.x * bhi(gd[0].w) + w4.y * bhi(gd[1].w) + w4.z * bhi(gd[2].w) + w4.w * bhi(gd[3].w);
        uint4 o;
        o.x = cvtpk(a0, a1); o.y = cvtpk(a2v, a3);
        o.z = cvtpk(a4, a5); o.w = cvtpk(a6, a7);
        *(uint4*)&Bs[buf][cc][px * 32 + bsw] = o;
    };

    // prologue. vmem order: pw0,pi0,g0(4),st0(4),pw1,pi1,pi2,g1(4).
    pwload(0);
    piload(0);
    gather(0, g[0]);
    stageA(0, 0);
    __builtin_amdgcn_sched_barrier(0);
    packwrite(0, 0);
    pwload(1);
    piload(1);
    piload(2);          // overwrites pi[0] (tap0 consumed); feeds gather(2)
    gather(1, g[1]);

#pragma unroll 2
    for (int i = 0; i < 18; ++i) {
        const int p = i & 1;
        __builtin_amdgcn_sched_barrier(0);
        if (i < 17)
            asm volatile("s_waitcnt vmcnt(4) lgkmcnt(0)" ::: "memory");
        else
            asm volatile("s_waitcnt vmcnt(0) lgkmcnt(0)" ::: "memory");
        __builtin_amdgcn_s_barrier();
        __builtin_amdgcn_sched_barrier(0);
        if (i < 17) {
            stageA(i + 1, 1 - p);          // 4 glds16, oldest this iter
            __builtin_amdgcn_sched_barrier(0);   // pin: stages before gathers
            packwrite(i + 1, 1 - p);       // consumes pw[(i+1)&1], g[(i+1)&1]
        }
        if (i + 2 < 18) pwload(i + 2);     // -> pw[i&1]
        if (i + 3 < 18) piload(i + 3);     // -> pi[(i+1)&1]
        if (i + 2 < 18) gather(i + 2, g[i & 1]);   // reads pi[i&1]
#pragma unroll
        for (int ss = 0; ss < 4; ++ss) {
            bf16x8 bfr[2];
#pragma unroll
            for (int ni = 0; ni < 2; ++ni) {
                const int row = wc * 32 + ni * 16 + l16;
                bfr[ni] = *(const bf16x8*)&Bs[p][ss][row * 32 + (quad ^ ((row >> 1) & 3)) * 8];
            }
#pragma unroll
            for (int mi = 0; mi < 2; ++mi) {
                const int row = wr * 32 + mi * 16 + l16;
                bf16x8 af = *(const bf16x8*)&As[p][ss][row * 32 + (quad ^ ((row >> 1) & 3)) * 8];
#pragma unroll
                for (int ni = 0; ni < 2; ++ni)
                    acc[mi][ni] = __builtin_amdgcn_mfma_f32_16x16x32_bf16(
                        af, bfr[ni], acc[mi][ni], 0, 0, 0);
            }
        }
    }

    const int m0 = wr * 32;
#pragma unroll
    for (int mi = 0; mi < 2; ++mi)
#pragma unroll
        for (int ni = 0; ni < 2; ++ni) {
            int nn = n0 + wc * 32 + ni * 16 + l16;
            int bidx = nn >> 12, hw = nn & 4095;
            float* op = out + (size_t)bidx * 256 * 4096 + hw;
#pragma unroll
            for (int r = 0; r < 4; ++r) {
                int m = m0 + mi * 16 + quad * 4 + r;
                op[(size_t)m * 4096] = acc[mi][ni][r] + bias[m];
            }
        }
}

// ---------------------------------------------------------------------------
extern "C" void kernel_launch(void* const* d_in, const int* in_sizes, int n_in,
                              void* d_out, int out_size, void* d_ws, size_t ws_size,
                              hipStream_t stream)
{
    const float* x      = (const float*)d_in[0];
    const float* w_off  = (const float*)d_in[1];
    const float* b_off  = (const float*)d_in[2];
    const float* weight = (const float*)d_in[3];
    const float* bias   = (const float*)d_in[4];
    float* out = (float*)d_out;
    char* ws = (char*)d_ws;

    // ws layout (19,300,352 B total):
    unsigned short* xT   = (unsigned short*)(ws);           //  8,388,608
    short*          a2   = (short*)(ws + 8388608);          //  1,179,648
    short*          wTb  = (short*)(ws + 9568256);          //    294,912
    float4*         planw= (float4*)(ws + 9863168);         //  4,718,592
    int4*           plani= (int4*)(ws + 14581760);          //  4,718,592 -> 19,300,352
    // om2p (4 split-K partials) aliases d_out; fully consumed by k_plan
    // before k_fused overwrites d_out. Stream-ordered.
    float*          om2p = (float*)d_out;

    hipLaunchKernelGGL(k_xt, dim3(64, 4, 4), dim3(256), 0, stream, x, xT);
    hipLaunchKernelGGL(k_wcvt_all, dim3(2880), dim3(256), 0, stream,
                       weight, w_off, a2, wTb);
    hipLaunchKernelGGL(k_omgemm, dim3(256, 4), dim3(256), 0, stream, wTb, xT, om2p);
    hipLaunchKernelGGL(k_plan, dim3(1152), dim3(256), 0, stream, om2p, b_off, planw, plani);
    hipLaunchKernelGGL(k_fused, dim3(256), dim3(1024), 0, stream,
                       a2, xT, planw, plani, bias, out);
}